// Round 5
// baseline (430.260 us; speedup 1.0000x reference)
//
#include <hip/hip_runtime.h>
#include <hip/hip_fp16.h>
#include <stdint.h>
#include <stddef.h>

#define N_NODES   40000
#define N_EDGES   640000
#define IN_FEATS  256
#define EDGE_FEATS 64
#define OUT_FEATS 128
#define NUM_HEADS 8
#define HD        16   // per-head dim

#define WH_BLOCKS   625            // 2500 waves * 16 nodes = 40000
#define HIST_BLOCKS 2500           // 2500 * 256 = 640000
#define FOLD_BLOCK  (WH_BLOCKS + HIST_BLOCKS)

typedef __attribute__((ext_vector_type(8))) short  short8;   // 8 x bf16 bits
typedef __attribute__((ext_vector_type(4))) float  floatx4;

__device__ inline short f2bf(float f) {
  union { float f; uint32_t u; } v; v.f = f;
  uint32_t r = v.u + 0x7fffu + ((v.u >> 16) & 1u);   // RNE
  return (short)(r >> 16);
}

__device__ inline short8 cvt8(float4 lo, float4 hi) {
  short8 r;
  r[0] = f2bf(lo.x); r[1] = f2bf(lo.y); r[2] = f2bf(lo.z); r[3] = f2bf(lo.w);
  r[4] = f2bf(hi.x); r[5] = f2bf(hi.y); r[6] = f2bf(hi.z); r[7] = f2bf(hi.w);
  return r;
}

__device__ inline float bflo(uint32_t w) {
  union { uint32_t u; float f; } v; v.u = w << 16; return v.f;
}
__device__ inline float bfhi(uint32_t w) {
  union { uint32_t u; float f; } v; v.u = w & 0xffff0000u; return v.f;
}

// ---------------- K1 (merged): wh_gemm(+ssd fold) | dst histogram | edge-W fold
// All three parts are mutually independent -> run concurrently in one dispatch.
__global__ __launch_bounds__(256) void fused_head_kernel(
    const float* __restrict__ A,        // node_feats [40000][256]
    const float* __restrict__ node_w,   // [128][256] fp32
    const float* __restrict__ bias,     // node_b [128]
    const float* __restrict__ edge_w, const float* __restrict__ edge_b,
    const float* __restrict__ attn, const int* __restrict__ dst,
    int* __restrict__ deg,
    float* __restrict__ Wfold, float* __restrict__ bfold,
    uint32_t* __restrict__ Whp,         // [40000][64] packed bf16 pairs
    float* __restrict__ s_src, float* __restrict__ s_dst) {
  int bid = blockIdx.x;
  int tid = threadIdx.x;

  if (bid < WH_BLOCKS) {
    // ---- wh_gemm: 4 waves/block, 16 nodes/wave, inline W->bf16 (bit-identical
    // to the old Wbf path), ssd folded out of fp32 accumulators.
    int wave = (bid * 256 + tid) >> 6;
    int lane = tid & 63;
    int m0 = wave * 16;
    int row = lane & 15, quad = lane >> 4;

    floatx4 acc[8];
    #pragma unroll
    for (int nt = 0; nt < 8; nt++) acc[nt] = (floatx4)(0.f);

    const float4* A4  = (const float4*)A;
    const float4* Wf4 = (const float4*)node_w;
    int a_base = ((m0 + row) * IN_FEATS + quad * 8) >> 2;   // float4 units

    #pragma unroll
    for (int s = 0; s < 8; s++) {
      float4 alo = A4[a_base + s * 8];
      float4 ahi = A4[a_base + s * 8 + 1];
      short8 af = cvt8(alo, ahi);
      #pragma unroll
      for (int nt = 0; nt < 8; nt++) {
        int fo = (nt * 16 + row) * IN_FEATS + s * 32 + quad * 8;  // elem offset
        float4 blo = Wf4[fo >> 2];
        float4 bhi = Wf4[(fo >> 2) + 1];
        short8 bf = cvt8(blo, bhi);      // same f2bf as old prep -> same bits
        acc[nt] = __builtin_amdgcn_mfma_f32_16x16x32_bf16(af, bf, acc[nt], 0, 0, 0);
      }
    }

    // attn scalars for this lane's d = row
    float as_lo[4], ad_lo[4], as_hi[4], ad_hi[4];
    #pragma unroll
    for (int nt = 0; nt < 4; nt++) {
      as_lo[nt] = attn[nt * 48 + row];
      ad_lo[nt] = attn[nt * 48 + 16 + row];
      as_hi[nt] = attn[(nt + 4) * 48 + row];
      ad_hi[nt] = attn[(nt + 4) * 48 + 16 + row];
    }

    #pragma unroll
    for (int nt = 0; nt < 4; nt++) {
      float blo_ = bias[nt * 16 + row];
      float bhi_ = bias[64 + nt * 16 + row];
      #pragma unroll
      for (int r = 0; r < 4; r++) {
        int m = m0 + quad * 4 + r;
        float lo = acc[nt][r] + blo_;
        float hi = acc[nt + 4][r] + bhi_;
        uint32_t dpk = (uint32_t)(uint16_t)f2bf(lo) |
                       ((uint32_t)(uint16_t)f2bf(hi) << 16);
        Whp[m * 64 + nt * 16 + row] = dpk;

        // ssd fold: reduce lo/hi * attn over the 16 rows of this quad group
        float v0 = lo * as_lo[nt];   // s_src head nt
        float v1 = lo * ad_lo[nt];   // s_dst head nt
        float v2 = hi * as_hi[nt];   // s_src head nt+4
        float v3 = hi * ad_hi[nt];   // s_dst head nt+4
        #pragma unroll
        for (int mk = 1; mk < 16; mk <<= 1) {
          v0 += __shfl_xor(v0, mk, 64);
          v1 += __shfl_xor(v1, mk, 64);
          v2 += __shfl_xor(v2, mk, 64);
          v3 += __shfl_xor(v3, mk, 64);
        }
        if (row == nt * 4 + r) {     // bijective (nt,r)->writer row
          s_src[m * 8 + nt]     = v0;
          s_dst[m * 8 + nt]     = v1;
          s_src[m * 8 + nt + 4] = v2;
          s_dst[m * 8 + nt + 4] = v3;
        }
      }
    }
  } else if (bid < FOLD_BLOCK) {
    // ---- dst histogram
    int e = (bid - WH_BLOCKS) * 256 + tid;   // exact 640000
    atomicAdd(&deg[dst[e]], 1);
  } else {
    // ---- edge-W fold: Wfold[h][k] = sum_d edge_w[h*16+d][k] * a_e[h][d]
    #pragma unroll
    for (int it = 0; it < 2; it++) {
      int idx = it * 256 + tid;              // 0..511 = 8 heads x 64 k
      int h = idx >> 6, k = idx & 63;
      float s = 0.f;
      #pragma unroll
      for (int d = 0; d < HD; d++)
        s += edge_w[(h * HD + d) * EDGE_FEATS + k] * attn[h * 48 + 32 + d];
      Wfold[h * EDGE_FEATS + k] = s;
    }
    if (tid < 8) {
      float b = 0.f;
      #pragma unroll
      for (int d = 0; d < HD; d++)
        b += edge_b[tid * HD + d] * attn[tid * 48 + 32 + d];
      bfold[tid] = b;
    }
  }
}

// ---------------- K2: register-staged single-barrier exclusive scan
// 1 block x 1024 threads; 40 chunks of 1024 preloaded into registers.
__global__ __launch_bounds__(1024) void scan_kernel(
    const int* __restrict__ deg, int* __restrict__ rs, int* __restrict__ cursor) {
  __shared__ int wsum[40][16];
  int tid = threadIdx.x;
  int lane = tid & 63, w = tid >> 6;

  int ex[40];   // exclusive-within-wave prefix per chunk (static indexing only)
  #pragma unroll
  for (int c = 0; c < 40; c++) {
    int i = c * 1024 + tid;
    int vv = (i < N_NODES) ? deg[i] : 0;
    int xv = vv;
    #pragma unroll
    for (int off = 1; off < 64; off <<= 1) {
      int y = __shfl_up(xv, off, 64);
      if (lane >= off) xv += y;
    }
    ex[c] = xv - vv;
    if (lane == 63) wsum[c][w] = xv;
  }
  __syncthreads();   // the only barrier

  int carry = 0;     // computed redundantly & identically by every thread
  #pragma unroll
  for (int c = 0; c < 40; c++) {
    int p = carry;
    #pragma unroll
    for (int j = 0; j < 16; j++) {
      int s = wsum[c][j];   // uniform address -> LDS broadcast
      if (j < w) p += s;
      carry += s;
    }
    int i = c * 1024 + tid;
    if (i < N_NODES) {
      int excl = p + ex[c];
      rs[i] = excl;
      cursor[i] = excl;
    }
  }
  if (tid == 0) rs[N_NODES] = carry;
}

// ---------------- K3: fused per-edge logits + scatter into CSR order
// Two 32 KB LDS phases (k4 0..7 then 8..15) instead of one 64 KB tile:
// same line-perfect coalescing (128 B contiguous per 8 lanes), identical
// accumulation order, but 5 blocks/CU (20 waves) instead of 2 (8 waves).
__global__ __launch_bounds__(256) void edge_scatter_kernel(
    const float* __restrict__ edge_feats, const int* __restrict__ src,
    const int* __restrict__ dst, const float* __restrict__ Wfold,
    const float* __restrict__ bfold, const float* __restrict__ s_src,
    const float* __restrict__ s_dst, int* __restrict__ cursor,
    uint32_t* __restrict__ rec) {   // rec: [N_EDGES][8] u32 (32 B records)
  __shared__ float4 efs[8 * 256];           // 32 KB: [kk][edge ^ kk]
  int tid = threadIdx.x;
  int e0 = blockIdx.x * 256;
  int e = e0 + tid;
  int s = src[e], d = dst[e];
  int pos = atomicAdd(&cursor[d], 1);       // issue early: latency overlaps load

  const float4* ss4 = (const float4*)(s_src + (size_t)s * 8);
  const float4* sd4 = (const float4*)(s_dst + (size_t)d * 8);
  float4 sa = ss4[0], sb = ss4[1];
  float4 da = sd4[0], db = sd4[1];

  float acc[8];
  #pragma unroll
  for (int h = 0; h < 8; h++) acc[h] = bfold[h];

  const float4* base = (const float4*)(edge_feats + (size_t)e0 * EDGE_FEATS);
  #pragma unroll
  for (int P = 0; P < 2; P++) {
    if (P) __syncthreads();                 // phase-0 reads done before reuse
    #pragma unroll
    for (int j = 0; j < 8; j++) {
      int q = j * 256 + tid;                // 0..2047
      int edge = q >> 3, kk = q & 7;        // 8 threads share an edge
      float4 v = base[edge * 16 + P * 8 + kk];
      efs[kk * 256 + (edge ^ kk)] = v;      // XOR swizzle: conflict-free
    }
    __syncthreads();
    #pragma unroll
    for (int kk = 0; kk < 8; kk++) {
      float4 f = efs[kk * 256 + (tid ^ kk)];
      int k4 = P * 8 + kk;
      #pragma unroll
      for (int h = 0; h < 8; h++) {
        const float* wr = Wfold + h * EDGE_FEATS + k4 * 4;  // wave-uniform
        acc[h] += f.x * wr[0] + f.y * wr[1] + f.z * wr[2] + f.w * wr[3];
      }
    }
  }

  float v[8];
  v[0] = acc[0] + sa.x + da.x; v[1] = acc[1] + sa.y + da.y;
  v[2] = acc[2] + sa.z + da.z; v[3] = acc[3] + sa.w + da.w;
  v[4] = acc[4] + sb.x + db.x; v[5] = acc[5] + sb.y + db.y;
  v[6] = acc[6] + sb.z + db.z; v[7] = acc[7] + sb.w + db.w;
  #pragma unroll
  for (int h = 0; h < 8; h++) v[h] = v[h] > 0.f ? v[h] : 0.2f * v[h];

  uint32_t pk[4];
  #pragma unroll
  for (int j = 0; j < 4; j++) {
    uint32_t lo = __half_as_ushort(__float2half_rn(v[2 * j]));
    uint32_t hi = __half_as_ushort(__float2half_rn(v[2 * j + 1]));
    pk[j] = lo | (hi << 16);
  }
  uint32_t* r = rec + (size_t)pos * 8;
  *(uint4*)r = make_uint4(pk[0], pk[1], pk[2], pk[3]);
  r[4] = (uint32_t)s;                       // same 32 B region -> same line
}

// ---------------- K4: per-node softmax (no-max exp) + aggregation
// 1 wave / node; lane covers output features (lane, lane+64).
// Records read SEQUENTIALLY (32 B each); only Whp row gather is random.
__global__ __launch_bounds__(256) void aggregate_kernel(
    const int* __restrict__ rs, const uint32_t* __restrict__ rec,
    const uint32_t* __restrict__ Whp, float* __restrict__ out) {
  int node = blockIdx.x * 4 + (threadIdx.x >> 6);
  int lane = threadIdx.x & 63;
  int h1 = lane >> 4;       // head of feature `lane` (0..3)
  int start = rs[node], end = rs[node + 1];
  uint32_t sh = (h1 & 1) * 16;
  bool hi_pair = (h1 & 2) != 0;

  float z1 = 0.f, z2 = 0.f, a1 = 0.f, a2 = 0.f;

  #define STEP(g, wv)                                                  \
    {                                                                  \
      uint32_t c1 = hi_pair ? (g).y : (g).x;                           \
      uint32_t c2 = hi_pair ? (g).w : (g).z;                           \
      float l1 = __half2float(__ushort_as_half((uint16_t)(c1 >> sh))); \
      float l2 = __half2float(__ushort_as_half((uint16_t)(c2 >> sh))); \
      float e1 = __expf(l1), e2 = __expf(l2);                          \
      z1 += e1; z2 += e2;                                              \
      a1 += e1 * bflo(wv); a2 += e2 * bfhi(wv);                        \
    }

  int i = start;
  for (; i + 3 < end; i += 4) {
    const uint32_t* r0 = rec + (size_t)i * 8;
    uint4 g0 = *(const uint4*)(r0);
    uint4 g1 = *(const uint4*)(r0 + 8);
    uint4 g2 = *(const uint4*)(r0 + 16);
    uint4 g3 = *(const uint4*)(r0 + 24);
    int s0 = (int)r0[4], s1 = (int)r0[12], s2 = (int)r0[20], s3 = (int)r0[28];
    uint32_t w0 = Whp[(size_t)s0 * 64 + lane];
    uint32_t w1 = Whp[(size_t)s1 * 64 + lane];
    uint32_t w2 = Whp[(size_t)s2 * 64 + lane];
    uint32_t w3 = Whp[(size_t)s3 * 64 + lane];
    STEP(g0, w0); STEP(g1, w1); STEP(g2, w2); STEP(g3, w3);
  }
  for (; i < end; i++) {
    const uint32_t* r0 = rec + (size_t)i * 8;
    uint4 g0 = *(const uint4*)(r0);
    int s0 = (int)r0[4];
    uint32_t w0 = Whp[(size_t)s0 * 64 + lane];
    STEP(g0, w0);
  }
  #undef STEP

  float o1 = (end > start) ? a1 / z1 : 0.f;
  float o2 = (end > start) ? a2 / z2 : 0.f;
  out[(size_t)node * OUT_FEATS + lane] = o1;
  out[(size_t)node * OUT_FEATS + 64 + lane] = o2;
}

extern "C" void kernel_launch(void* const* d_in, const int* in_sizes, int n_in,
                              void* d_out, int out_size, void* d_ws, size_t ws_size,
                              hipStream_t stream) {
  const float* node_feats = (const float*)d_in[0];
  const float* edge_feats = (const float*)d_in[1];
  const int*   src        = (const int*)d_in[2];
  const int*   dst        = (const int*)d_in[3];
  const float* node_w     = (const float*)d_in[4];
  const float* node_b     = (const float*)d_in[5];
  const float* edge_w     = (const float*)d_in[6];
  const float* edge_b     = (const float*)d_in[7];
  const float* attn       = (const float*)d_in[8];
  float* out = (float*)d_out;

  char* ws = (char*)d_ws;
  size_t off = 0;
  auto alloc = [&](size_t bytes) {
    void* p = ws + off;
    off += (bytes + 255) & ~(size_t)255;
    return p;
  };
  uint32_t* Whp      = (uint32_t*)alloc((size_t)N_NODES * 64 * 4);      // 10.24 MB
  float*    s_src    = (float*)alloc((size_t)N_NODES * NUM_HEADS * 4);  // 1.28 MB
  float*    s_dst    = (float*)alloc((size_t)N_NODES * NUM_HEADS * 4);  // 1.28 MB
  uint32_t* rec      = (uint32_t*)alloc((size_t)N_EDGES * 32);          // 20.48 MB
  int*      deg      = (int*)alloc((size_t)N_NODES * 4);
  int*      rs       = (int*)alloc((size_t)(N_NODES + 1) * 4);
  int*      cursor   = (int*)alloc((size_t)N_NODES * 4);
  float*    Wfold    = (float*)alloc(NUM_HEADS * EDGE_FEATS * 4);
  float*    bfold    = (float*)alloc(NUM_HEADS * 4);

  hipMemsetAsync(deg, 0, (size_t)N_NODES * 4, stream);

  fused_head_kernel<<<WH_BLOCKS + HIST_BLOCKS + 1, 256, 0, stream>>>(
      node_feats, node_w, node_b, edge_w, edge_b, attn, dst, deg,
      Wfold, bfold, Whp, s_src, s_dst);
  scan_kernel<<<1, 1024, 0, stream>>>(deg, rs, cursor);
  edge_scatter_kernel<<<N_EDGES / 256, 256, 0, stream>>>(
      edge_feats, src, dst, Wfold, bfold, s_src, s_dst, cursor, rec);
  aggregate_kernel<<<N_NODES / 4, 256, 0, stream>>>(rs, rec, Whp, out);
}

// Round 8
// 405.952 us; speedup vs baseline: 1.0599x; 1.0599x over previous
//
#include <hip/hip_runtime.h>
#include <hip/hip_fp16.h>
#include <stdint.h>
#include <stddef.h>

#define N_NODES   40000
#define N_EDGES   640000
#define IN_FEATS  256
#define EDGE_FEATS 64
#define OUT_FEATS 128
#define NUM_HEADS 8
#define HD        16   // per-head dim

#define WH_BLOCKS   625            // 2500 waves * 16 nodes = 40000
#define HIST_BLOCKS 2500           // 2500 * 256 = 640000
#define FOLD_BLOCK  (WH_BLOCKS + HIST_BLOCKS)

typedef __attribute__((ext_vector_type(8))) short  short8;   // 8 x bf16 bits
typedef __attribute__((ext_vector_type(4))) float  floatx4;

__device__ inline short f2bf(float f) {
  union { float f; uint32_t u; } v; v.f = f;
  uint32_t r = v.u + 0x7fffu + ((v.u >> 16) & 1u);   // RNE
  return (short)(r >> 16);
}

__device__ inline short8 cvt8(float4 lo, float4 hi) {
  short8 r;
  r[0] = f2bf(lo.x); r[1] = f2bf(lo.y); r[2] = f2bf(lo.z); r[3] = f2bf(lo.w);
  r[4] = f2bf(hi.x); r[5] = f2bf(hi.y); r[6] = f2bf(hi.z); r[7] = f2bf(hi.w);
  return r;
}

__device__ inline float bflo(uint32_t w) {
  union { uint32_t u; float f; } v; v.u = w << 16; return v.f;
}
__device__ inline float bfhi(uint32_t w) {
  union { uint32_t u; float f; } v; v.u = w & 0xffff0000u; return v.f;
}

// ---------------- K1 (merged): wh_gemm(+ssd fold) | dst histogram | edge-W fold
// All three parts are mutually independent -> run concurrently in one dispatch.
__global__ __launch_bounds__(256) void fused_head_kernel(
    const float* __restrict__ A,        // node_feats [40000][256]
    const float* __restrict__ node_w,   // [128][256] fp32
    const float* __restrict__ bias,     // node_b [128]
    const float* __restrict__ edge_w, const float* __restrict__ edge_b,
    const float* __restrict__ attn, const int* __restrict__ dst,
    int* __restrict__ deg,
    float* __restrict__ Wfold, float* __restrict__ bfold,
    uint32_t* __restrict__ Whp,         // [40000][64] packed bf16 pairs
    float* __restrict__ s_src, float* __restrict__ s_dst) {
  int bid = blockIdx.x;
  int tid = threadIdx.x;

  if (bid < WH_BLOCKS) {
    // ---- wh_gemm: 4 waves/block, 16 nodes/wave, inline W->bf16 (bit-identical
    // to the old Wbf path), ssd folded out of fp32 accumulators.
    int wave = (bid * 256 + tid) >> 6;
    int lane = tid & 63;
    int m0 = wave * 16;
    int row = lane & 15, quad = lane >> 4;

    floatx4 acc[8];
    #pragma unroll
    for (int nt = 0; nt < 8; nt++) acc[nt] = (floatx4)(0.f);

    const float4* A4  = (const float4*)A;
    const float4* Wf4 = (const float4*)node_w;
    int a_base = ((m0 + row) * IN_FEATS + quad * 8) >> 2;   // float4 units

    #pragma unroll
    for (int s = 0; s < 8; s++) {
      float4 alo = A4[a_base + s * 8];
      float4 ahi = A4[a_base + s * 8 + 1];
      short8 af = cvt8(alo, ahi);
      #pragma unroll
      for (int nt = 0; nt < 8; nt++) {
        int fo = (nt * 16 + row) * IN_FEATS + s * 32 + quad * 8;  // elem offset
        float4 blo = Wf4[fo >> 2];
        float4 bhi = Wf4[(fo >> 2) + 1];
        short8 bf = cvt8(blo, bhi);      // same f2bf as old prep -> same bits
        acc[nt] = __builtin_amdgcn_mfma_f32_16x16x32_bf16(af, bf, acc[nt], 0, 0, 0);
      }
    }

    // attn scalars for this lane's d = row
    float as_lo[4], ad_lo[4], as_hi[4], ad_hi[4];
    #pragma unroll
    for (int nt = 0; nt < 4; nt++) {
      as_lo[nt] = attn[nt * 48 + row];
      ad_lo[nt] = attn[nt * 48 + 16 + row];
      as_hi[nt] = attn[(nt + 4) * 48 + row];
      ad_hi[nt] = attn[(nt + 4) * 48 + 16 + row];
    }

    #pragma unroll
    for (int nt = 0; nt < 4; nt++) {
      float blo_ = bias[nt * 16 + row];
      float bhi_ = bias[64 + nt * 16 + row];
      #pragma unroll
      for (int r = 0; r < 4; r++) {
        int m = m0 + quad * 4 + r;
        float lo = acc[nt][r] + blo_;
        float hi = acc[nt + 4][r] + bhi_;
        uint32_t dpk = (uint32_t)(uint16_t)f2bf(lo) |
                       ((uint32_t)(uint16_t)f2bf(hi) << 16);
        Whp[m * 64 + nt * 16 + row] = dpk;

        // ssd fold: reduce lo/hi * attn over the 16 rows of this quad group
        float v0 = lo * as_lo[nt];   // s_src head nt
        float v1 = lo * ad_lo[nt];   // s_dst head nt
        float v2 = hi * as_hi[nt];   // s_src head nt+4
        float v3 = hi * ad_hi[nt];   // s_dst head nt+4
        #pragma unroll
        for (int mk = 1; mk < 16; mk <<= 1) {
          v0 += __shfl_xor(v0, mk, 64);
          v1 += __shfl_xor(v1, mk, 64);
          v2 += __shfl_xor(v2, mk, 64);
          v3 += __shfl_xor(v3, mk, 64);
        }
        if (row == nt * 4 + r) {     // bijective (nt,r)->writer row
          s_src[m * 8 + nt]     = v0;
          s_dst[m * 8 + nt]     = v1;
          s_src[m * 8 + nt + 4] = v2;
          s_dst[m * 8 + nt + 4] = v3;
        }
      }
    }
  } else if (bid < FOLD_BLOCK) {
    // ---- dst histogram
    int e = (bid - WH_BLOCKS) * 256 + tid;   // exact 640000
    atomicAdd(&deg[dst[e]], 1);
  } else {
    // ---- edge-W fold: Wfold[h][k] = sum_d edge_w[h*16+d][k] * a_e[h][d]
    #pragma unroll
    for (int it = 0; it < 2; it++) {
      int idx = it * 256 + tid;              // 0..511 = 8 heads x 64 k
      int h = idx >> 6, k = idx & 63;
      float s = 0.f;
      #pragma unroll
      for (int d = 0; d < HD; d++)
        s += edge_w[(h * HD + d) * EDGE_FEATS + k] * attn[h * 48 + 32 + d];
      Wfold[h * EDGE_FEATS + k] = s;
    }
    if (tid < 8) {
      float b = 0.f;
      #pragma unroll
      for (int d = 0; d < HD; d++)
        b += edge_b[tid * HD + d] * attn[tid * 48 + 32 + d];
      bfold[tid] = b;
    }
  }
}

// ---------------- K2: register-staged single-barrier exclusive scan
// 1 block x 1024 threads; 40 chunks of 1024 preloaded into registers.
__global__ __launch_bounds__(1024) void scan_kernel(
    const int* __restrict__ deg, int* __restrict__ rs, int* __restrict__ cursor) {
  __shared__ int wsum[40][16];
  int tid = threadIdx.x;
  int lane = tid & 63, w = tid >> 6;

  int ex[40];   // exclusive-within-wave prefix per chunk (static indexing only)
  #pragma unroll
  for (int c = 0; c < 40; c++) {
    int i = c * 1024 + tid;
    int vv = (i < N_NODES) ? deg[i] : 0;
    int xv = vv;
    #pragma unroll
    for (int off = 1; off < 64; off <<= 1) {
      int y = __shfl_up(xv, off, 64);
      if (lane >= off) xv += y;
    }
    ex[c] = xv - vv;
    if (lane == 63) wsum[c][w] = xv;
  }
  __syncthreads();   // the only barrier

  int carry = 0;     // computed redundantly & identically by every thread
  #pragma unroll
  for (int c = 0; c < 40; c++) {
    int p = carry;
    #pragma unroll
    for (int j = 0; j < 16; j++) {
      int s = wsum[c][j];   // uniform address -> LDS broadcast
      if (j < w) p += s;
      carry += s;
    }
    int i = c * 1024 + tid;
    if (i < N_NODES) {
      int excl = p + ex[c];
      rs[i] = excl;
      cursor[i] = excl;
    }
  }
  if (tid == 0) rs[N_NODES] = carry;
}

// ---------------- K3: fused per-edge logits + scatter into CSR order
// SINGLE-phase staging (all 16 loads issued back-to-back: 16-deep MLP per
// thread) with a 128-edge / 128-thread / 32 KB tile: 5 blocks/CU = 10
// waves/CU (vs 8 at 64 KB) AND full load depth (R5's two-phase split halved
// MLP and regressed). Same swizzle, identical accumulation order.
__global__ __launch_bounds__(128) void edge_scatter_kernel(
    const float* __restrict__ edge_feats, const int* __restrict__ src,
    const int* __restrict__ dst, const float* __restrict__ Wfold,
    const float* __restrict__ bfold, const float* __restrict__ s_src,
    const float* __restrict__ s_dst, int* __restrict__ cursor,
    uint32_t* __restrict__ rec) {   // rec: [N_EDGES][8] u32 (32 B records)
  __shared__ float4 efs[16 * 128];          // 32 KB: [k4][edge ^ (k4&7)]
  int tid = threadIdx.x;
  int e0 = blockIdx.x * 128;
  int e = e0 + tid;
  int s = src[e], d = dst[e];
  int pos = atomicAdd(&cursor[d], 1);       // issue early: latency overlaps load

  const float4* ss4 = (const float4*)(s_src + (size_t)s * 8);
  const float4* sd4 = (const float4*)(s_dst + (size_t)d * 8);
  float4 sa = ss4[0], sb = ss4[1];
  float4 da = sd4[0], db = sd4[1];

  // cooperative coalesced load + LDS transpose (all 16 loads in flight)
  const float4* base = (const float4*)(edge_feats + (size_t)e0 * EDGE_FEATS);
  #pragma unroll
  for (int j = 0; j < 16; j++) {
    int p = j * 128 + tid;                  // linear float4 index, coalesced
    float4 v = base[p];
    int k4 = p & 15;
    int edge = p >> 4;
    efs[k4 * 128 + (edge ^ (k4 & 7))] = v;  // XOR swizzle: balanced banks
  }
  __syncthreads();

  float acc[8];
  #pragma unroll
  for (int h = 0; h < 8; h++) acc[h] = bfold[h];
  #pragma unroll
  for (int k4 = 0; k4 < 16; k4++) {
    float4 f = efs[k4 * 128 + (tid ^ (k4 & 7))];
    #pragma unroll
    for (int h = 0; h < 8; h++) {
      const float* wr = Wfold + h * EDGE_FEATS + k4 * 4;  // wave-uniform
      acc[h] += f.x * wr[0] + f.y * wr[1] + f.z * wr[2] + f.w * wr[3];
    }
  }
  float v[8];
  v[0] = acc[0] + sa.x + da.x; v[1] = acc[1] + sa.y + da.y;
  v[2] = acc[2] + sa.z + da.z; v[3] = acc[3] + sa.w + da.w;
  v[4] = acc[4] + sb.x + db.x; v[5] = acc[5] + sb.y + db.y;
  v[6] = acc[6] + sb.z + db.z; v[7] = acc[7] + sb.w + db.w;
  #pragma unroll
  for (int h = 0; h < 8; h++) v[h] = v[h] > 0.f ? v[h] : 0.2f * v[h];

  uint32_t pk[4];
  #pragma unroll
  for (int j = 0; j < 4; j++) {
    uint32_t lo = __half_as_ushort(__float2half_rn(v[2 * j]));
    uint32_t hi = __half_as_ushort(__float2half_rn(v[2 * j + 1]));
    pk[j] = lo | (hi << 16);
  }
  uint32_t* r = rec + (size_t)pos * 8;
  *(uint4*)r = make_uint4(pk[0], pk[1], pk[2], pk[3]);
  r[4] = (uint32_t)s;                       // same 32 B region -> same line
}

// ---------------- K4: per-node softmax (no-max exp) + aggregation
// 1 wave / node; lane covers output features (lane, lane+64).
// Records read SEQUENTIALLY (32 B each); only Whp row gather is random.
__global__ __launch_bounds__(256) void aggregate_kernel(
    const int* __restrict__ rs, const uint32_t* __restrict__ rec,
    const uint32_t* __restrict__ Whp, float* __restrict__ out) {
  int node = blockIdx.x * 4 + (threadIdx.x >> 6);
  int lane = threadIdx.x & 63;
  int h1 = lane >> 4;       // head of feature `lane` (0..3)
  int start = rs[node], end = rs[node + 1];
  uint32_t sh = (h1 & 1) * 16;
  bool hi_pair = (h1 & 2) != 0;

  float z1 = 0.f, z2 = 0.f, a1 = 0.f, a2 = 0.f;

  #define STEP(g, wv)                                                  \
    {                                                                  \
      uint32_t c1 = hi_pair ? (g).y : (g).x;                           \
      uint32_t c2 = hi_pair ? (g).w : (g).z;                           \
      float l1 = __half2float(__ushort_as_half((uint16_t)(c1 >> sh))); \
      float l2 = __half2float(__ushort_as_half((uint16_t)(c2 >> sh))); \
      float e1 = __expf(l1), e2 = __expf(l2);                          \
      z1 += e1; z2 += e2;                                              \
      a1 += e1 * bflo(wv); a2 += e2 * bfhi(wv);                        \
    }

  int i = start;
  for (; i + 3 < end; i += 4) {
    const uint32_t* r0 = rec + (size_t)i * 8;
    uint4 g0 = *(const uint4*)(r0);
    uint4 g1 = *(const uint4*)(r0 + 8);
    uint4 g2 = *(const uint4*)(r0 + 16);
    uint4 g3 = *(const uint4*)(r0 + 24);
    int s0 = (int)r0[4], s1 = (int)r0[12], s2 = (int)r0[20], s3 = (int)r0[28];
    uint32_t w0 = Whp[(size_t)s0 * 64 + lane];
    uint32_t w1 = Whp[(size_t)s1 * 64 + lane];
    uint32_t w2 = Whp[(size_t)s2 * 64 + lane];
    uint32_t w3 = Whp[(size_t)s3 * 64 + lane];
    STEP(g0, w0); STEP(g1, w1); STEP(g2, w2); STEP(g3, w3);
  }
  for (; i < end; i++) {
    const uint32_t* r0 = rec + (size_t)i * 8;
    uint4 g0 = *(const uint4*)(r0);
    int s0 = (int)r0[4];
    uint32_t w0 = Whp[(size_t)s0 * 64 + lane];
    STEP(g0, w0);
  }
  #undef STEP

  float o1 = (end > start) ? a1 / z1 : 0.f;
  float o2 = (end > start) ? a2 / z2 : 0.f;
  out[(size_t)node * OUT_FEATS + lane] = o1;
  out[(size_t)node * OUT_FEATS + 64 + lane] = o2;
}

extern "C" void kernel_launch(void* const* d_in, const int* in_sizes, int n_in,
                              void* d_out, int out_size, void* d_ws, size_t ws_size,
                              hipStream_t stream) {
  const float* node_feats = (const float*)d_in[0];
  const float* edge_feats = (const float*)d_in[1];
  const int*   src        = (const int*)d_in[2];
  const int*   dst        = (const int*)d_in[3];
  const float* node_w     = (const float*)d_in[4];
  const float* node_b     = (const float*)d_in[5];
  const float* edge_w     = (const float*)d_in[6];
  const float* edge_b     = (const float*)d_in[7];
  const float* attn       = (const float*)d_in[8];
  float* out = (float*)d_out;

  char* ws = (char*)d_ws;
  size_t off = 0;
  auto alloc = [&](size_t bytes) {
    void* p = ws + off;
    off += (bytes + 255) & ~(size_t)255;
    return p;
  };
  uint32_t* Whp      = (uint32_t*)alloc((size_t)N_NODES * 64 * 4);      // 10.24 MB
  float*    s_src    = (float*)alloc((size_t)N_NODES * NUM_HEADS * 4);  // 1.28 MB
  float*    s_dst    = (float*)alloc((size_t)N_NODES * NUM_HEADS * 4);  // 1.28 MB
  uint32_t* rec      = (uint32_t*)alloc((size_t)N_EDGES * 32);          // 20.48 MB
  int*      deg      = (int*)alloc((size_t)N_NODES * 4);
  int*      rs       = (int*)alloc((size_t)(N_NODES + 1) * 4);
  int*      cursor   = (int*)alloc((size_t)N_NODES * 4);
  float*    Wfold    = (float*)alloc(NUM_HEADS * EDGE_FEATS * 4);
  float*    bfold    = (float*)alloc(NUM_HEADS * 4);

  hipMemsetAsync(deg, 0, (size_t)N_NODES * 4, stream);

  fused_head_kernel<<<WH_BLOCKS + HIST_BLOCKS + 1, 256, 0, stream>>>(
      node_feats, node_w, node_b, edge_w, edge_b, attn, dst, deg,
      Wfold, bfold, Whp, s_src, s_dst);
  scan_kernel<<<1, 1024, 0, stream>>>(deg, rs, cursor);
  edge_scatter_kernel<<<N_EDGES / 128, 128, 0, stream>>>(
      edge_feats, src, dst, Wfold, bfold, s_src, s_dst, cursor, rec);
  aggregate_kernel<<<N_NODES / 4, 256, 0, stream>>>(rs, rec, Whp, out);
}